// Round 16
// baseline (261.615 us; speedup 1.0000x reference)
//
#include <hip/hip_runtime.h>

typedef unsigned short u16;
typedef unsigned int u32;
typedef short bf16x8 __attribute__((ext_vector_type(8)));
typedef float f32x4 __attribute__((ext_vector_type(4)));
typedef unsigned short u16x4 __attribute__((ext_vector_type(4)));
typedef unsigned short u16x8 __attribute__((ext_vector_type(8)));

__device__ __forceinline__ u16 f32_to_bf16(float f) {
    u32 u = __float_as_uint(f);
    u += 0x7FFFu + ((u >> 16) & 1u);
    return (u16)(u >> 16);
}
// truncating cast (p in [0,1], P-matrix only)
__device__ __forceinline__ short f32_to_bf16_trunc(float f) {
    return (short)(__float_as_uint(f) >> 16);
}

// native exp2 (v_exp_f32); fallback via __expf if builtin missing
#if __has_builtin(__builtin_amdgcn_exp2f)
#define EXP2(x) __builtin_amdgcn_exp2f(x)
#else
#define EXP2(x) __expf((x) * 0.69314718056f)
#endif

// async global->LDS, 16B per lane; lds pointer must be wave-uniform
__device__ __forceinline__ void gl_lds16(const u16* g, u16* l) {
    __builtin_amdgcn_global_load_lds(
        (const __attribute__((address_space(1))) u32*)g,
        (__attribute__((address_space(3))) u32*)l, 16, 0, 0);
}

// Bank-conflict swizzle for 64B-row LDS tiles read as (row*32 + chunk*8) u16:
// physical chunk = logical chunk ^ ((row>>1)&3). Folded into the DMA *source*
// address (per-lane), so LDS writes stay contiguous.

// ---------------------------------------------------------------------------
// bulk fp32 -> bf16 cast; slice y==7 builds the RoPE cos/sin tables
// ---------------------------------------------------------------------------
struct CastArgs {
    const float* src[8];
    u16* dst[8];
    int n4[8];
};

__global__ __launch_bounds__(256) void cast_kernel(CastArgs a) {
    const int y = blockIdx.y;
    const int n4 = a.n4[y];
    if (y == 7) {
        // RoPE trig tables: dst[7] = cos table (fp32), sin table right after.
        const float* s = a.src[7];
        float* c  = (float*)a.dst[7];
        float* sn = c + 131072;
        for (int i = blockIdx.x * blockDim.x + threadIdx.x; i < n4; i += gridDim.x * blockDim.x) {
            f32x4 v = *(const f32x4*)&s[(size_t)i * 4];
            f32x4 cv, sv;
            #pragma unroll
            for (int j = 0; j < 4; j++) {
                float ss, cc;
                __sincosf(v[j], &ss, &cc);
                sv[j] = ss; cv[j] = cc;
            }
            *(f32x4*)&c[(size_t)i * 4]  = cv;
            *(f32x4*)&sn[(size_t)i * 4] = sv;
        }
        return;
    }
    const float* s = a.src[y];
    u16* d = a.dst[y];
    for (int i = blockIdx.x * blockDim.x + threadIdx.x; i < n4; i += gridDim.x * blockDim.x) {
        f32x4 v = *(const f32x4*)&s[(size_t)i * 4];
        u16x4 o = { f32_to_bf16(v[0]), f32_to_bf16(v[1]), f32_to_bf16(v[2]), f32_to_bf16(v[3]) };
        *(u16x4*)&d[(size_t)i * 4] = o;
    }
}

#define GK 1024
#define GN 1024
#define GM 4096

// ---------------------------------------------------------------------------
// QKV projection GEMM + RoPE. 128x128 tile, BK=32, grid (32 m, 8 n, 3 z).
// Single-barrier double-buffer main loop (round-12 verified, -20% vs the
// two-barrier version). z=0 Q: [t][HD] bf16 scaled 0.125*log2(e);
// z=1 K: KT[h][kb][ks][kl][32]; z=2 V: VT[h][kb][ks][dv][32'].
// RoPE trig from precomputed tables (csT) with in-line fallback.
// ---------------------------------------------------------------------------
__global__ __launch_bounds__(256) void gemm_rope(
    const u16* __restrict__ A0, const u16* __restrict__ A1, const u16* __restrict__ A2,
    const u16* __restrict__ W0, const u16* __restrict__ W1, const u16* __restrict__ W2,
    u16* __restrict__ C0, u16* __restrict__ C1, u16* __restrict__ C2,
    const float* __restrict__ freqs, const float* __restrict__ csT)
{
    __shared__ u16 SM[16384];   // [buf][ A 4096 | B 4096 ] u16, double-buffered

    const int z = blockIdx.z;
    const u16* A = (z == 0) ? A0 : ((z == 1) ? A1 : A2);
    const u16* W = (z == 0) ? W0 : ((z == 1) ? W1 : W2);
    u16* Cb      = (z == 0) ? C0 : ((z == 1) ? C1 : C2);
    const float ascale = (z == 0) ? 0.18033688f : 1.0f;   // 0.125 * log2(e)

    const int tid  = threadIdx.x;
    const int w    = tid >> 6;
    const int lane = tid & 63;
    const int quad = lane >> 4;
    const int l16  = lane & 15;
    const int m0 = blockIdx.x * 128;
    const int n0 = blockIdx.y * 128;
    const int wm = (w >> 1) * 64;
    const int wn = (w & 1) * 64;

    const int sr = tid >> 2;
    const int sc = (((tid & 3) ^ ((tid >> 3) & 3))) * 8;   // swizzled source chunk
    const size_t aoff0 = (size_t)(m0 + sr) * GK + sc;
    const size_t aoff1 = aoff0 + (size_t)64 * GK;
    const size_t boff0 = (size_t)(n0 + sr) * GK + sc;
    const size_t boff1 = boff0 + (size_t)64 * GK;

    const int csw = (quad ^ ((l16 >> 1) & 3)) * 8;          // swizzled read chunk

    f32x4 acc[4][4];
    for (int i = 0; i < 4; i++)
        for (int j = 0; j < 4; j++) acc[i][j] = 0.f;

    // prologue: stage tile 0 -> buf 0
    {
        u16* Ab = SM;
        gl_lds16(A + aoff0, &Ab[w * 512]);
        gl_lds16(A + aoff1, &Ab[2048 + w * 512]);
        gl_lds16(W + boff0, &Ab[4096 + w * 512]);
        gl_lds16(W + boff1, &Ab[4096 + 2048 + w * 512]);
    }

    for (int it = 0; it < 32; ++it) {
        __syncthreads();   // DMA for tile it drained; buf^1 free for prefetch
        if (it < 31) {
            const int k0 = (it + 1) * 32;
            u16* Ab = SM + ((it + 1) & 1) * 8192;
            gl_lds16(A + aoff0 + k0, &Ab[w * 512]);
            gl_lds16(A + aoff1 + k0, &Ab[2048 + w * 512]);
            gl_lds16(W + boff0 + k0, &Ab[4096 + w * 512]);
            gl_lds16(W + boff1 + k0, &Ab[4096 + 2048 + w * 512]);
        }
        const u16* As = SM + (it & 1) * 8192;
        const u16* Bs = As + 4096;

        bf16x8 af[4], bfr[4];
        for (int t = 0; t < 4; t++) {
            af[t]  = *(const bf16x8*)&As[(wm + t * 16 + l16) * 32 + csw];
            bfr[t] = *(const bf16x8*)&Bs[(wn + t * 16 + l16) * 32 + csw];
        }
        for (int mt = 0; mt < 4; mt++)
            for (int nt = 0; nt < 4; nt++)
                acc[mt][nt] = __builtin_amdgcn_mfma_f32_16x16x32_bf16(
                    af[mt], bfr[nt], acc[mt][nt], 0, 0, 0);
    }
    __syncthreads();   // all compute done; SM dead -> reusable as scratch
    // per-wave scratch (wave-private)
    u16* tr = SM + w * 1152;  // 16 rows x 72 u16

    const int hh = (n0 + wn) >> 6;
    const size_t tb = (size_t)hh * 262144 + (size_t)((m0 + wm) >> 6) * 4096;
    const float* snT = csT ? (csT + 131072) : (const float*)0;

    if (z != 2) {
        for (int mt = 0; mt < 4; mt++) {
            #pragma unroll
            for (int r = 0; r < 4; r++) {
                int m = m0 + wm + mt * 16 + quad * 4 + r;
                float v0 = acc[mt][0][r];
                float v1 = acc[mt][1][r];
                float s0, c0, s1, c1;
                if (csT) {
                    c0 = csT[m * 32 + l16];      s0 = snT[m * 32 + l16];
                    c1 = csT[m * 32 + 16 + l16]; s1 = snT[m * 32 + 16 + l16];
                } else {
                    __sincosf(freqs[m * 32 + l16], &s0, &c0);
                    __sincosf(freqs[m * 32 + 16 + l16], &s1, &c1);
                }
                int row = quad * 4 + r;
                tr[row * 72 + l16]      = f32_to_bf16((v0 * c0 - v1 * s0) * ascale);
                tr[row * 72 + 16 + l16] = f32_to_bf16((v1 * c1 + v0 * s1) * ascale);
                tr[row * 72 + 32 + l16] = f32_to_bf16(acc[mt][2][r] * ascale);
                tr[row * 72 + 48 + l16] = f32_to_bf16(acc[mt][3][r] * ascale);
            }
            // wave-private transpose read: lane -> row l16, cols quad*16..+16
            u16x8 va = *(const u16x8*)&tr[l16 * 72 + quad * 16];
            u16x8 vb = *(const u16x8*)&tr[l16 * 72 + quad * 16 + 8];
            if (z == 0) {
                size_t base = (size_t)(m0 + wm + mt * 16 + l16) * GN + n0 + wn + quad * 16;
                *(u16x8*)&Cb[base]     = va;
                *(u16x8*)&Cb[base + 8] = vb;
            } else {
                // K half-split: dk = quad*16 + c -> half ks = quad>>1, within = (quad&1)*16 + c
                size_t base = tb + (size_t)(quad >> 1) * 2048
                            + (size_t)(mt * 16 + l16) * 32 + (quad & 1) * 16;
                *(u16x8*)&Cb[base]     = va;
                *(u16x8*)&Cb[base + 8] = vb;
            }
        }
    } else {
        // V: VT[h][kb][ks][dv][32'], kappa within each 32-key half
        for (int mt = 0; mt < 4; mt++) {
            float o0[4], o1[4];
            for (int r = 0; r < 4; r++) {
                int m = m0 + wm + mt * 16 + quad * 4 + r;
                float v0 = acc[mt][0][r];
                float v1 = acc[mt][1][r];
                float s0, c0, s1, c1;
                if (csT) {
                    c0 = csT[m * 32 + l16];      s0 = snT[m * 32 + l16];
                    c1 = csT[m * 32 + 16 + l16]; s1 = snT[m * 32 + 16 + l16];
                } else {
                    __sincosf(freqs[m * 32 + l16], &s0, &c0);
                    __sincosf(freqs[m * 32 + 16 + l16], &s1, &c1);
                }
                o0[r] = v0 * c0 - v1 * s0;
                o1[r] = v1 * c1 + v0 * s1;
            }
            const int ks = mt >> 1;                       // key half
            const int sl = 4 * (mt & 1) + 8 * quad;       // slot within half (r adds 0..3)
            const size_t hb = tb + (size_t)ks * 2048 + sl;
            u16x4 u;
            u = { f32_to_bf16(o0[0]), f32_to_bf16(o0[1]), f32_to_bf16(o0[2]), f32_to_bf16(o0[3]) };
            *(u16x4*)&Cb[hb + (size_t)l16 * 32] = u;
            u = { f32_to_bf16(o1[0]), f32_to_bf16(o1[1]), f32_to_bf16(o1[2]), f32_to_bf16(o1[3]) };
            *(u16x4*)&Cb[hb + (size_t)(16 + l16) * 32] = u;
            u = { f32_to_bf16(acc[mt][2][0]), f32_to_bf16(acc[mt][2][1]),
                  f32_to_bf16(acc[mt][2][2]), f32_to_bf16(acc[mt][2][3]) };
            *(u16x4*)&Cb[hb + (size_t)(32 + l16) * 32] = u;
            u = { f32_to_bf16(acc[mt][3][0]), f32_to_bf16(acc[mt][3][1]),
                  f32_to_bf16(acc[mt][3][2]), f32_to_bf16(acc[mt][3][3]) };
            *(u16x4*)&Cb[hb + (size_t)(48 + l16) * 32] = u;
        }
    }
}

// ---------------------------------------------------------------------------
// Output projection GEMM. Tile 64x128, grid (64 m, 8 n) = 512 blocks = 2/CU.
// Single-barrier double-buffer protocol (round-12 verified).
// ---------------------------------------------------------------------------
__global__ __launch_bounds__(256) void gemm_out(
    const u16* __restrict__ A, const u16* __restrict__ W, float* __restrict__ C)
{
    __shared__ u16 SM[12288];  // [buf][ A 2048 | B 4096 ] u16, double-buffered

    const int tid  = threadIdx.x;
    const int w    = tid >> 6;
    const int lane = tid & 63;
    const int quad = lane >> 4;
    const int l16  = lane & 15;
    const int m0 = blockIdx.x * 64;
    const int n0 = blockIdx.y * 128;
    const int wm = (w >> 1) * 32;
    const int wn = (w & 1) * 64;

    const int sr = tid >> 2;
    const int sc = (((tid & 3) ^ ((tid >> 3) & 3))) * 8;   // swizzled source chunk
    const size_t aoff  = (size_t)(m0 + sr) * GK + sc;
    const size_t boff0 = (size_t)(n0 + sr) * GK + sc;
    const size_t boff1 = boff0 + (size_t)64 * GK;

    const int csw = (quad ^ ((l16 >> 1) & 3)) * 8;

    f32x4 acc[2][4];
    for (int i = 0; i < 2; i++)
        for (int j = 0; j < 4; j++) acc[i][j] = 0.f;

    // prologue: stage tile 0 -> buf 0
    {
        u16* Ab = SM;
        gl_lds16(A + aoff,  &Ab[w * 512]);
        gl_lds16(W + boff0, &Ab[2048 + w * 512]);
        gl_lds16(W + boff1, &Ab[2048 + 2048 + w * 512]);
    }

    for (int it = 0; it < 32; ++it) {
        __syncthreads();   // DMA for tile it drained; buf^1 free
        if (it < 31) {
            const int k0 = (it + 1) * 32;
            u16* Ab = SM + ((it + 1) & 1) * 6144;
            gl_lds16(A + aoff + k0,  &Ab[w * 512]);
            gl_lds16(W + boff0 + k0, &Ab[2048 + w * 512]);
            gl_lds16(W + boff1 + k0, &Ab[2048 + 2048 + w * 512]);
        }
        const u16* As = SM + (it & 1) * 6144;
        const u16* Bs = As + 2048;

        bf16x8 af[2], bfr[4];
        for (int t = 0; t < 2; t++)
            af[t] = *(const bf16x8*)&As[(wm + t * 16 + l16) * 32 + csw];
        for (int t = 0; t < 4; t++)
            bfr[t] = *(const bf16x8*)&Bs[(wn + t * 16 + l16) * 32 + csw];
        for (int mt = 0; mt < 2; mt++)
            for (int nt = 0; nt < 4; nt++)
                acc[mt][nt] = __builtin_amdgcn_mfma_f32_16x16x32_bf16(
                    af[mt], bfr[nt], acc[mt][nt], 0, 0, 0);
    }
    __syncthreads();   // all compute done; SM dead -> reusable as scratch

    // per-wave fp32 transpose scratch: 16 rows x 68 floats
    float* tr = (float*)SM + w * 1088;
    for (int mt = 0; mt < 2; mt++) {
        #pragma unroll
        for (int nt = 0; nt < 4; nt++)
            #pragma unroll
            for (int r = 0; r < 4; r++)
                tr[(quad * 4 + r) * 68 + nt * 16 + l16] = acc[mt][nt][r];
        size_t base = (size_t)(m0 + wm + mt * 16 + l16) * GN + n0 + wn + quad * 16;
        #pragma unroll
        for (int c = 0; c < 4; c++) {
            f32x4 v = *(const f32x4*)&tr[l16 * 68 + quad * 16 + c * 4];
            *(f32x4*)&C[base + c * 4] = v;
        }
    }
}

// ---------------------------------------------------------------------------
// Flash attention, causal. KVBLK=128: each DMA tile stages TWO 64-key
// sub-tiles (K 16KB + V 16KB), halving the barrier count (33 vs 65) — the
// measured bottleneck is the per-iteration barrier rendezvous + DMA drain
// (R14: more waves made it worse; R2/R5: LDS/VALU volume free).
// LDS = KV double buffer 65536 B ONLY -> hardware residency capped at
// EXACTLY 2 blocks/CU. Failure analysis of R7/8/9: launch_bounds' 2nd arg
// never caps residency; all failing variants had 32KB LDS (5-resident),
// all passing ones were LDS-capped <=3. 2-resident is the safest regime.
// 1-D decomposition (wave owns 16 q rows x all keys): no cross-wave
// exchange, register-only epilogue (ones-MFMA denominator at ls_acc[0];
// o[nv][r] = out[q=l16][dv=nv*16+quad*4+r] stored as aligned u16x4).
// Grid 1024, qb = 63-(id>>4) long-first; exp2-domain softmax (Q pre-scaled
// 0.125*log2e, -16*log2e seeded); single barrier per 128-key tile.
// XCD locality: h = (id&7)*2 + ((id>>3)&1) keeps 2 heads (2MB KV) per XCD L2.
// ---------------------------------------------------------------------------
__global__ __launch_bounds__(256, 2) void attn_kernel(
    const u16* __restrict__ Qb, const u16* __restrict__ KT,
    const u16* __restrict__ VTg, u16* __restrict__ valsb)
{
    __shared__ __align__(16) u16 KV[2][16384];  // [buf][ K 8192 | V 8192 ] u16

    const int tid  = threadIdx.x;
    const int w    = tid >> 6;
    const int lane = tid & 63;
    const int quad = lane >> 4;
    const int l16  = lane & 15;
    const int HD = 1024;

    const int id = blockIdx.x;
    const int h  = (id & 7) * 2 + ((id >> 3) & 1);   // 2 heads per XCD -> L2-local KV
    const int qb = 63 - (id >> 4);                   // long blocks first

    const u16* kt = KT  + (size_t)h * 262144;
    const u16* vt = VTg + (size_t)h * 262144;

    // swizzled per-lane DMA source offset within a 1KB (16-row) span
    const int dmaoff = (lane >> 2) * 32 + ((lane & 3) ^ ((lane >> 3) & 3)) * 8;
    const int csw = (quad ^ ((l16 >> 1) & 3)) * 8;   // swizzled read chunk

    // ones A-fragment for the denominator MFMA
    bf16x8 ones;
    #pragma unroll
    for (int i = 0; i < 8; i++) ones[i] = (short)0x3F80;   // bf16 1.0
    const f32x4 seed = { -23.0831204f, -23.0831204f, -23.0831204f, -23.0831204f };

    // Q B-frags for this wave's 16 q rows (2 dk halves)
    const size_t qrow = (size_t)(qb * 64 + w * 16 + l16);
    const bf16x8 bq0 = *(const bf16x8*)&Qb[qrow * HD + h * 64 + quad * 8];
    const bf16x8 bq1 = *(const bf16x8*)&Qb[qrow * HD + h * 64 + 32 + quad * 8];
    const int q_local = w * 16 + l16;

    f32x4 o[4];
    #pragma unroll
    for (int i = 0; i < 4; i++) o[i] = 0.f;
    f32x4 ls_acc = 0.f;

    const int T = (qb >> 1) + 1;   // 128-key tiles

    // prologue DMA: tile 0 -> buf 0 (K 16KB + V 16KB, 8 x 1KB per wave)
    #pragma unroll
    for (int i = 0; i < 4; i++) {
        gl_lds16(kt + i * 2048 + w * 512 + dmaoff, &KV[0][i * 2048 + w * 512]);
        gl_lds16(vt + i * 2048 + w * 512 + dmaoff, &KV[0][8192 + i * 2048 + w * 512]);
    }

    for (int t = 0; t < T; ++t) {
        __syncthreads();  // DMA for tile t drained; buf^1 free
        if (t < T - 1) {
            const int nb = (t + 1) & 1;
            const u16* ksrc = kt + (size_t)(t + 1) * 8192;
            const u16* vsrc = vt + (size_t)(t + 1) * 8192;
            #pragma unroll
            for (int i = 0; i < 4; i++) {
                gl_lds16(ksrc + i * 2048 + w * 512 + dmaoff, &KV[nb][i * 2048 + w * 512]);
                gl_lds16(vsrc + i * 2048 + w * 512 + dmaoff, &KV[nb][8192 + i * 2048 + w * 512]);
            }
        }
        const u16* base = &KV[t & 1][0];

        #pragma unroll
        for (int sub = 0; sub < 2; ++sub) {
            const int kb = 2 * t + sub;
            if (kb > qb) break;            // wave-uniform (t, sub, qb uniform)
            const u16* Ksb = base + sub * 4096;
            const u16* Vsb = base + 8192 + sub * 4096;

            // S^T = K * Q^T (exp2 domain, bias seeded into accumulator)
            // lane q = l16, key = nt2*16 + quad*4 + r (within 64-key sub-tile)
            f32x4 s[4];
            #pragma unroll
            for (int nt2 = 0; nt2 < 4; nt2++) {
                bf16x8 ak0 = *(const bf16x8*)&Ksb[(nt2 * 16 + l16) * 32 + csw];
                bf16x8 ak1 = *(const bf16x8*)&Ksb[2048 + (nt2 * 16 + l16) * 32 + csw];
                f32x4 z4 = seed;
                z4 = __builtin_amdgcn_mfma_f32_16x16x32_bf16(ak0, bq0, z4, 0, 0, 0);
                s[nt2] = __builtin_amdgcn_mfma_f32_16x16x32_bf16(ak1, bq1, z4, 0, 0, 0);
            }

            if (kb == qb) {  // diagonal: mask key > q
                #pragma unroll
                for (int nt2 = 0; nt2 < 4; nt2++)
                    #pragma unroll
                    for (int r = 0; r < 4; r++)
                        if (nt2 * 16 + quad * 4 + r > q_local) s[nt2][r] = -1e30f;
            }

            // V frags issued before exp so lgkmcnt hides under VALU
            bf16x8 av[8];
            #pragma unroll
            for (int nv = 0; nv < 4; nv++) {
                av[nv * 2]     = *(const bf16x8*)&Vsb[(nv * 16 + l16) * 32 + csw];
                av[nv * 2 + 1] = *(const bf16x8*)&Vsb[2048 + (nv * 16 + l16) * 32 + csw];
            }

            // p = exp2(s): one v_exp_f32 per element
            #pragma unroll
            for (int nt2 = 0; nt2 < 4; nt2++)
                #pragma unroll
                for (int r = 0; r < 4; r++)
                    s[nt2][r] = EXP2(s[nt2][r]);

            bf16x8 bp0 = { f32_to_bf16_trunc(s[0][0]), f32_to_bf16_trunc(s[0][1]),
                           f32_to_bf16_trunc(s[0][2]), f32_to_bf16_trunc(s[0][3]),
                           f32_to_bf16_trunc(s[1][0]), f32_to_bf16_trunc(s[1][1]),
                           f32_to_bf16_trunc(s[1][2]), f32_to_bf16_trunc(s[1][3]) };
            bf16x8 bp1 = { f32_to_bf16_trunc(s[2][0]), f32_to_bf16_trunc(s[2][1]),
                           f32_to_bf16_trunc(s[2][2]), f32_to_bf16_trunc(s[2][3]),
                           f32_to_bf16_trunc(s[3][0]), f32_to_bf16_trunc(s[3][1]),
                           f32_to_bf16_trunc(s[3][2]), f32_to_bf16_trunc(s[3][3]) };

            // denominator via matrix pipe: ls_acc += ones x P (both key halves)
            ls_acc = __builtin_amdgcn_mfma_f32_16x16x32_bf16(ones, bp0, ls_acc, 0, 0, 0);
            ls_acc = __builtin_amdgcn_mfma_f32_16x16x32_bf16(ones, bp1, ls_acc, 0, 0, 0);

            // PV: 4 independent accumulator chains
            #pragma unroll
            for (int nv = 0; nv < 4; nv++) {
                o[nv] = __builtin_amdgcn_mfma_f32_16x16x32_bf16(av[nv * 2], bp0, o[nv], 0, 0, 0);
                o[nv] = __builtin_amdgcn_mfma_f32_16x16x32_bf16(av[nv * 2 + 1], bp1, o[nv], 0, 0, 0);
            }
        }
    }

    // ---- register-only epilogue: no LDS, no barriers ----
    // ls_acc rows are identical (ones x P) -> per-lane denominator for q row
    // l16 is ls_acc[0]. o[nv][r] = out[q=l16][dv=nv*16+quad*4+r].
    const float inv = 1.f / ls_acc[0];
    const size_t obase = (size_t)(qb * 64 + w * 16 + l16) * HD + h * 64;
    #pragma unroll
    for (int nv = 0; nv < 4; nv++) {
        u16x4 st = { f32_to_bf16(o[nv][0] * inv), f32_to_bf16(o[nv][1] * inv),
                     f32_to_bf16(o[nv][2] * inv), f32_to_bf16(o[nv][3] * inv) };
        *(u16x4*)&valsb[obase + nv * 16 + quad * 4] = st;
    }
}

// ---------------------------------------------------------------------------
// ws layout (u16 idx): qc 0 | kc 4M | vc 8M | wqc 12M | wkc 13M | wvc 14M |
// woc 15M | Qb 16M | KT 20M | VT 24M | trig tables 28M (if ws allows).
// valsb reuses qc. Base 56 MiB + 1 MiB tables.
// ---------------------------------------------------------------------------
extern "C" void kernel_launch(void* const* d_in, const int* in_sizes, int n_in,
                              void* d_out, int out_size, void* d_ws, size_t ws_size,
                              hipStream_t stream) {
    const float* q     = (const float*)d_in[0];
    const float* k     = (const float*)d_in[1];
    const float* v     = (const float*)d_in[2];
    const float* freqs = (const float*)d_in[4];
    const float* wq    = (const float*)d_in[5];
    const float* wk    = (const float*)d_in[6];
    const float* wv    = (const float*)d_in[7];
    const float* wo    = (const float*)d_in[8];

    u16* B = (u16*)d_ws;
    u16* qc  = B;
    u16* kc  = B + (size_t)4194304;
    u16* vc  = B + (size_t)8388608;
    u16* wqc = B + (size_t)12582912;
    u16* wkc = B + (size_t)13631488;
    u16* wvc = B + (size_t)14680064;
    u16* woc = B + (size_t)15728640;
    u16* Qb  = B + (size_t)16777216;
    u16* KT  = B + (size_t)20971520;
    u16* VT  = B + (size_t)25165824;
    u16* valsb = qc;   // qc dead after gemm_rope reads it

    // trig tables after VT: cos [131072 floats] then sin [131072 floats]
    const size_t tab_off_u16 = 29360128;                 // byte 58720256
    const size_t need_bytes  = 58720256 + 2 * 131072 * sizeof(float);
    float* csT = (ws_size >= need_bytes) ? (float*)(B + tab_off_u16) : (float*)0;

    CastArgs ca;
    ca.src[0] = q;  ca.dst[0] = qc;  ca.n4[0] = 1048576;
    ca.src[1] = k;  ca.dst[1] = kc;  ca.n4[1] = 1048576;
    ca.src[2] = v;  ca.dst[2] = vc;  ca.n4[2] = 1048576;
    ca.src[3] = wq; ca.dst[3] = wqc; ca.n4[3] = 262144;
    ca.src[4] = wk; ca.dst[4] = wkc; ca.n4[4] = 262144;
    ca.src[5] = wv; ca.dst[5] = wvc; ca.n4[5] = 262144;
    ca.src[6] = wo; ca.dst[6] = woc; ca.n4[6] = 262144;
    ca.src[7] = freqs; ca.dst[7] = (u16*)csT; ca.n4[7] = csT ? 32768 : 0;
    cast_kernel<<<dim3(1024, 8), 256, 0, stream>>>(ca);

    gemm_rope<<<dim3(32, 8, 3), 256, 0, stream>>>(
        qc, kc, vc, wqc, wkc, wvc, Qb, KT, VT, freqs, csT);

    attn_kernel<<<dim3(1024), 256, 0, stream>>>(Qb, KT, VT, valsb);

    gemm_out<<<dim3(64, 8), 256, 0, stream>>>(valsb, woc, (float*)d_out);
}